// Round 6
// baseline (191324.255 us; speedup 1.0000x reference)
//
#include <hip/hip_runtime.h>

// GRU decoder B=64,T=512,IN=H=512,L=2. Persistent pipelined grid:
//   blocks [0,128)  = cell A (layer0 @ t),  blocks [128,256) = cell B (layer1 @ t-1)
// 256 blocks x 512 threads (1 block/CU, 8 waves, 2/SIMD). Block = 4 cols;
// wave = 4 cols x K-octant. Weights in LDS (48KB, staged once).
//
// R6 = R5 with fixed asm modifier order (offset: must precede sc0 sc1).
// FENCE-FREE (R4 proved correctness of no-acquire-fence) with the ONE proven
// load pattern: issue + s_waitcnt FUSED in a single asm block (the barrier's poll
// idiom, alive since R0). No split waits (R2/R3 crashed: compiler spilled in-flight
// asm dests), no __hip_atomic_load (R4: lowered to HBM RMW, 280GB writes).
// h-state reads are fused-group sc0sc1 loads:
//   cell A: ld8_coh per chunk (1 base + offset:256*q, h stride in [k][b] is 256B)
//   cell B: ld16_coh per 8-k group (x-group + h-group, 2 bases)
// Latency ~600cy paid once per group, overlapped across 2 waves/SIMD. FMA order
// bit-identical to R1. No per-tick L2 invalidation -> x/weights stay cache-warm.

#define NBLK 256
#define NTHR 512
#define Bsz  64
#define Tlen 512
#define Kd   512
#define Hd   512
#define KC   64
#define LP   67   // LDS pitch: scalar transpose writes land 2-way max (free)

__device__ __forceinline__ float sigf(float v){ return 1.0f/(1.0f+__expf(-v)); }
__device__ __forceinline__ float tanhx(float v){
  float e=__expf(-2.0f*fabsf(v)); float t=(1.0f-e)/(1.0f+e); return v<0.0f?-t:t;
}
__device__ __forceinline__ unsigned umin2(unsigned a, unsigned b){ return a<b?a:b; }

// coherent (L1/L2-bypassing, L3-committed) store
__device__ __forceinline__ void st_coh(float* p, float v){
  asm volatile("global_store_dword %0, %1, off sc0 sc1" :: "v"(p), "v"(v) : "memory");
}
__device__ __forceinline__ void st_coh_u(unsigned* p, unsigned v){
  asm volatile("global_store_dword %0, %1, off sc0 sc1" :: "v"(p), "v"(v) : "memory");
}
__device__ __forceinline__ void wait_vm0(){ asm volatile("s_waitcnt vmcnt(0)" ::: "memory"); }

// ---- fused coherent loads: issue + wait in ONE asm block (proven-safe idiom) ----
// 8 consecutive k at stride 256B from one base
__device__ __forceinline__ void ld8_coh(float* d, const float* base){
  asm volatile(
    "global_load_dword %0, %8, off sc0 sc1\n\t"
    "global_load_dword %1, %8, off offset:256 sc0 sc1\n\t"
    "global_load_dword %2, %8, off offset:512 sc0 sc1\n\t"
    "global_load_dword %3, %8, off offset:768 sc0 sc1\n\t"
    "global_load_dword %4, %8, off offset:1024 sc0 sc1\n\t"
    "global_load_dword %5, %8, off offset:1280 sc0 sc1\n\t"
    "global_load_dword %6, %8, off offset:1536 sc0 sc1\n\t"
    "global_load_dword %7, %8, off offset:1792 sc0 sc1\n\t"
    "s_waitcnt vmcnt(0)"
    : "=&v"(d[0]),"=&v"(d[1]),"=&v"(d[2]),"=&v"(d[3]),
      "=&v"(d[4]),"=&v"(d[5]),"=&v"(d[6]),"=&v"(d[7])
    : "v"(base) : "memory");
}
// 8 x-values + 8 h-values (two bases), one wait
__device__ __forceinline__ void ld16_coh(float* dx, float* dh,
                                         const float* bx, const float* bh){
  asm volatile(
    "global_load_dword %0, %16, off sc0 sc1\n\t"
    "global_load_dword %1, %16, off offset:256 sc0 sc1\n\t"
    "global_load_dword %2, %16, off offset:512 sc0 sc1\n\t"
    "global_load_dword %3, %16, off offset:768 sc0 sc1\n\t"
    "global_load_dword %4, %16, off offset:1024 sc0 sc1\n\t"
    "global_load_dword %5, %16, off offset:1280 sc0 sc1\n\t"
    "global_load_dword %6, %16, off offset:1536 sc0 sc1\n\t"
    "global_load_dword %7, %16, off offset:1792 sc0 sc1\n\t"
    "global_load_dword %8, %17, off sc0 sc1\n\t"
    "global_load_dword %9, %17, off offset:256 sc0 sc1\n\t"
    "global_load_dword %10, %17, off offset:512 sc0 sc1\n\t"
    "global_load_dword %11, %17, off offset:768 sc0 sc1\n\t"
    "global_load_dword %12, %17, off offset:1024 sc0 sc1\n\t"
    "global_load_dword %13, %17, off offset:1280 sc0 sc1\n\t"
    "global_load_dword %14, %17, off offset:1536 sc0 sc1\n\t"
    "global_load_dword %15, %17, off offset:1792 sc0 sc1\n\t"
    "s_waitcnt vmcnt(0)"
    : "=&v"(dx[0]),"=&v"(dx[1]),"=&v"(dx[2]),"=&v"(dx[3]),
      "=&v"(dx[4]),"=&v"(dx[5]),"=&v"(dx[6]),"=&v"(dx[7]),
      "=&v"(dh[0]),"=&v"(dh[1]),"=&v"(dh[2]),"=&v"(dh[3]),
      "=&v"(dh[4]),"=&v"(dh[5]),"=&v"(dh[6]),"=&v"(dh[7])
    : "v"(bx), "v"(bh) : "memory");
}
__device__ __forceinline__ float ld1_coh(const float* p){
  float v;
  asm volatile("global_load_dword %0, %1, off sc0 sc1\n\ts_waitcnt vmcnt(0)"
               : "=&v"(v) : "v"(p) : "memory");
  return v;
}

// Grid barrier: release = (sc0sc1 data stores) + vmcnt(0) + slot store.
// acquire side needs NO cache maintenance: all cross-tick data is read sc0sc1
// (R4 proved no-fence correctness end-to-end).
__device__ __forceinline__ void grid_barrier(unsigned* slots, unsigned target, int tid){
  wait_vm0();                 // every wave: my coherent stores are committed at L3
  __syncthreads();            // whole block done storing
  if(tid == 0) st_coh_u(slots + blockIdx.x, target);
  if(tid < 64){
    const unsigned* p0 = slots + tid;
    for(;;){
      unsigned a,b,c,d;
      asm volatile(
        "global_load_dword %0, %4, off sc0 sc1\n\t"
        "global_load_dword %1, %5, off sc0 sc1\n\t"
        "global_load_dword %2, %6, off sc0 sc1\n\t"
        "global_load_dword %3, %7, off sc0 sc1\n\t"
        "s_waitcnt vmcnt(0)"
        : "=&v"(a),"=&v"(b),"=&v"(c),"=&v"(d)
        : "v"(p0), "v"(p0+64), "v"(p0+128), "v"(p0+192)
        : "memory");
      unsigned m = umin2(umin2(a,b), umin2(c,d));
      #pragma unroll
      for(int off=32; off; off>>=1)
        m = umin2(m, (unsigned)__shfl_xor((int)m, off, 64));
      if(m >= target) break;
      __builtin_amdgcn_s_sleep(1);
    }
  }
  __syncthreads();
  // NO acquire fence: coherent reads bypass L1/L2, nothing can be stale.
}

// stage+transpose chunk ch of x[b][t][.] into sbuf[k_local][b], pitch LP
__device__ __forceinline__ void stageA(float* sbuf, const float* __restrict__ x,
                                       int t, int ch, int tid){
  #pragma unroll
  for(int it=0; it<2; ++it){
    int q  = it*NTHR + tid;          // 0..1023
    int b  = q >> 4;
    int k4 = (q & 15) << 2;
    const float4 v = *(const float4*)(x + ((size_t)b*Tlen + t)*Kd + ch*KC + k4);
    sbuf[(k4+0)*LP + b] = v.x;
    sbuf[(k4+1)*LP + b] = v.y;
    sbuf[(k4+2)*LP + b] = v.z;
    sbuf[(k4+3)*LP + b] = v.w;
  }
}

// 4-k-step of all 24 weight streams from LDS (broadcast b128 reads), FMA order
// bit-identical to the original per-k sequence.
__device__ __forceinline__ void gru_fma(const float* __restrict__ wlds, int kg,
                                        const float* xv, const float* hv,
                                        float* pr, float* pz, float* pni, float* pnh)
{
  float4 w[24];
  #pragma unroll
  for(int s = 0; s < 24; ++s)
    w[s] = *(const float4*)(wlds + s*Kd + kg);
  #pragma unroll
  for(int u = 0; u < 4; ++u){
    #pragma unroll
    for(int c = 0; c < 4; ++c){
      pr[c]  = fmaf(xv[u], (&w[     c].x)[u], pr[c]);
      pz[c]  = fmaf(xv[u], (&w[ 4 + c].x)[u], pz[c]);
      pni[c] = fmaf(xv[u], (&w[ 8 + c].x)[u], pni[c]);
      pr[c]  = fmaf(hv[u], (&w[12 + c].x)[u], pr[c]);
      pz[c]  = fmaf(hv[u], (&w[16 + c].x)[u], pz[c]);
      pnh[c] = fmaf(hv[u], (&w[20 + c].x)[u], pnh[c]);
    }
  }
}

extern "C" __global__ void __launch_bounds__(NTHR, 2)
gru_persist(const float* __restrict__ x,     // [B,T,IN]
            const float* __restrict__ eh,    // [L,B,H]
            const float* __restrict__ Wih,   // [L,3H,IN]
            const float* __restrict__ Whh,   // [L,3H,H]
            const float* __restrict__ bih,   // [L,3H]
            const float* __restrict__ bhh,   // [L,3H]
            float* __restrict__ out,         // [B,T,H] ++ [L,B,H]
            float* __restrict__ ws)
{
  __shared__ float smem[2*KC*LP];   // A: x staging dbuf; reused as reduction buffer
  __shared__ float wlds[24*Kd];     // 48KB: this block's weights, stream s = mat*12+g*4+c

  unsigned* slots = (unsigned*)ws;            // 256 monotonic tick slots
  float* h0T = ws + 256;                      // 2 bufs x [512][64]
  float* h1T = h0T + 2*Kd*Bsz;
  float* htail = out + (size_t)Bsz*Tlen*Hd;

  const int tid  = threadIdx.x;
  const int lane = tid & 63;                                   // batch
  const int wv   = __builtin_amdgcn_readfirstlane(tid >> 6);   // wave id 0..7
  const int cell = blockIdx.x >> 7;                            // 0=layer0, 1=layer1
  const int cb   = blockIdx.x & 127;
  const int col0 = cb * 4;                                     // block's 4 cols
  unsigned bar = 1;

  // ---- one-time: stage this block's 24 weight rows into LDS ----
  {
    const float* WiC = Wih + (size_t)cell*3*Hd*Kd;
    const float* WhC = Whh + (size_t)cell*3*Hd*Kd;
    #pragma unroll 1
    for(int i = tid; i < 24*(Kd/4); i += NTHR){  // 3072 float4s, 6 iters/thread
      const int s   = i >> 7;                    // stream 0..23
      const int k4  = (i & 127) << 2;
      const int mat = (s >= 12);
      const int r   = s - 12*mat;
      const int g   = r >> 2, c = r & 3;
      const float* src = (mat ? WhC : WiC) + ((size_t)(g*Hd + col0 + c))*Kd + k4;
      *(float4*)(wlds + (size_t)s*Kd + k4) = *(const float4*)src;
    }
  }

  // ---- init: encoder_h -> parity-1 state bufs, transposed [k][b], coherent ----
  {
    int i = blockIdx.x*NTHR + tid;            // 131072 threads, 65536 items
    if(i < 2*Kd*Bsz){
      int l = i >> 15, k = (i >> 6) & 511, b = i & 63;
      float v = eh[(size_t)(l*Bsz + b)*Hd + k];
      st_coh((l ? h1T : h0T) + Kd*Bsz + k*Bsz + b, v);
    }
  }
  grid_barrier(slots, bar, tid); bar++;       // also fences wlds staging for this block

  // epilogue biases for this wave's col (clamped for waves 4..7; unused there)
  const int ec = wv & 3;
  const int ecol = col0 + ec;
  const float bi0 = bih[cell*1536 + 0*Hd + ecol] + bhh[cell*1536 + 0*Hd + ecol];
  const float bi1 = bih[cell*1536 + 1*Hd + ecol] + bhh[cell*1536 + 1*Hd + ecol];
  const float bi2 = bih[cell*1536 + 2*Hd + ecol];
  const float bh2 = bhh[cell*1536 + 2*Hd + ecol];

  for(int t = 0; t <= Tlen; ++t){
    const bool active = (cell == 0) ? (t < Tlen) : (t >= 1);
    if(active){
      const int s = (cell == 0) ? t : (t - 1);
      float* hbase = (cell == 0) ? h0T : h1T;
      const float* hprev = hbase + ((s+1)&1)*Kd*Bsz;
      float*       hout  = hbase + (s&1)*Kd*Bsz;
      const float* inT   = h0T + (s&1)*Kd*Bsz;      // cell B input (written by A last tick)

      float pr[4]={0,0,0,0}, pz[4]={0,0,0,0}, pni[4]={0,0,0,0}, pnh[4]={0,0,0,0};

      if(cell == 0){
        // per chunk: fused 8-h coherent load, then x-stage(next), then FMA.
        stageA(smem, x, t, 0, tid);
        __syncthreads();
        #pragma unroll
        for(int ch = 0; ch < 8; ++ch){
          const float* cur = smem + (ch&1)*(KC*LP);
          float hbuf[8];
          ld8_coh(hbuf, hprev + ((size_t)((ch<<6)+(wv<<3)))*Bsz + lane);
          if(ch < 7) stageA(smem + ((ch+1)&1)*(KC*LP), x, t, ch+1, tid);
          #pragma unroll
          for(int jj = 0; jj < 8; jj += 4){
            const int kl = (wv<<3) + jj;         // wave's interleaved sub-slice
            const int kg = (ch<<6) + kl;
            float xv[4];
            #pragma unroll
            for(int u = 0; u < 4; ++u)
              xv[u] = cur[(kl+u)*LP + lane];
            gru_fma(wlds, kg, xv, &hbuf[jj], pr, pz, pni, pnh);
          }
          __syncthreads();
        }
      } else {
        // per 8-k group: fused 16-load (x+h), then FMA. K-octant per wave.
        const int kg0 = (wv<<6);
        #pragma unroll
        for(int g = 0; g < 8; ++g){
          const int kg = kg0 + (g<<3);
          float xg[8], hg[8];
          ld16_coh(xg, hg, inT + (size_t)kg*Bsz + lane,
                          hprev + (size_t)kg*Bsz + lane);
          gru_fma(wlds, kg,   xg,   hg,   pr, pz, pni, pnh);
          gru_fma(wlds, kg+4, xg+4, hg+4, pr, pz, pni, pnh);
        }
        __syncthreads();   // match A's pre-reduction state (smem free)
      }

      // ---- ksplit-8 reduction via LDS (aliases smem; guarded by syncs) ----
      float* red = smem;   // [(c*4+p)*8 + w][64]
      #pragma unroll
      for(int c = 0; c < 4; ++c){
        red[(((c<<2)+0)*8 + wv)*64 + lane] = pr[c];
        red[(((c<<2)+1)*8 + wv)*64 + lane] = pz[c];
        red[(((c<<2)+2)*8 + wv)*64 + lane] = pni[c];
        red[(((c<<2)+3)*8 + wv)*64 + lane] = pnh[c];
      }
      __syncthreads();
      if(wv < 4){
        const int c = wv;
        const int col = col0 + c;
        const float hkeep = ld1_coh(hprev + col*Bsz + lane);
        float spr=0.f, spz=0.f, spni=0.f, spnh=0.f;
        #pragma unroll
        for(int w = 0; w < 8; ++w){
          spr  += red[(((c<<2)+0)*8 + w)*64 + lane];
          spz  += red[(((c<<2)+1)*8 + w)*64 + lane];
          spni += red[(((c<<2)+2)*8 + w)*64 + lane];
          spnh += red[(((c<<2)+3)*8 + w)*64 + lane];
        }
        const float r = sigf(spr + bi0);
        const float z = sigf(spz + bi1);
        const float n = tanhx(spni + bi2 + r*(spnh + bh2));
        const float hnew = (1.0f - z)*n + z*hkeep;
        st_coh(hout + col*Bsz + lane, hnew);                       // coherent, 256B/wave
        if(cell == 1)
          out[((size_t)lane*Tlen + s)*Hd + col] = hnew;            // normal store
      }
    }
    grid_barrier(slots, bar, tid); bar++;
  }

  // ---- tail: htail[l][b][c] from parity-1 bufs (coherent reads) ----
  {
    int i = blockIdx.x*NTHR + tid;
    if(i < 2*Kd*Bsz){
      int l = i >> 15, b = (i >> 9) & 63, c = i & 511;
      const float* src = (l ? h1T : h0T) + Kd*Bsz;
      htail[i] = ld1_coh(src + c*Bsz + b);
    }
  }
}

extern "C" void kernel_launch(void* const* d_in, const int* in_sizes, int n_in,
                              void* d_out, int out_size, void* d_ws, size_t ws_size,
                              hipStream_t stream) {
  (void)in_sizes; (void)n_in; (void)out_size; (void)ws_size;
  const float* x   = (const float*)d_in[0];
  const float* eh  = (const float*)d_in[1];
  const float* Wih = (const float*)d_in[2];
  const float* Whh = (const float*)d_in[3];
  const float* bih = (const float*)d_in[4];
  const float* bhh = (const float*)d_in[5];
  float* out = (float*)d_out;
  float* ws  = (float*)d_ws;

  hipMemsetAsync(d_ws, 0, 1024, stream);   // zero barrier slots

  void* args[] = {(void*)&x, (void*)&eh, (void*)&Wih, (void*)&Whh,
                  (void*)&bih, (void*)&bhh, (void*)&out, (void*)&ws};
  hipLaunchCooperativeKernel((const void*)gru_persist, dim3(NBLK), dim3(NTHR),
                             args, 0, stream);
}

// Round 8
// 41751.230 us; speedup vs baseline: 4.5825x; 4.5825x over previous
//
#include <hip/hip_runtime.h>

// GRU decoder B=64,T=512,IN=H=512,L=2. Persistent pipelined grid:
//   blocks [0,128)  = cell A (layer0 @ t),  blocks [128,256) = cell B (layer1 @ t-1)
// 256 blocks x 512 threads (1 block/CU, 8 waves). Block = 4 cols; wave = K-octant.
// Weights in LDS (48KB). h-state in d_ws [k][b], written sc0sc1 (write-through to
// L3 = coherence point), read with NORMAL cached loads after per-tick acquire fence.
//
// R8 = R7 resubmitted (R7 hit GPUAcquisitionTimeout; never ran).
// STARVE THE BARRIER POLL. R6 proved sc0sc1 loads are per-lane uncoalesced
// (~24-32x traffic amplification; 611GB HBM for 25GB useful). R0/R1's poll used the
// same pattern: 64 lanes x 4 slots = 16KB of L3 sectors per iteration per block,
// continuously during every barrier wait -> L3 saturation is the hidden tick cost.
// Fix: arrival = atomicAdd into 8 padded counters (fire-and-forget at L3);
// detect = lane0-only fused 8-load poll (512B/iter, 256 polling lanes chip-wide).
// Plus: cell A pre-stages next x chunk0 into LDS inside the barrier (x is read-only,
// fence-independent) -> staging off the critical path. Compute path = R1 verbatim.

#define NBLK 256
#define NTHR 512
#define Bsz  64
#define Tlen 512
#define Kd   512
#define Hd   512
#define KC   64
#define LP   67   // LDS pitch: scalar transpose writes land 2-way max (free)

__device__ __forceinline__ float sigf(float v){ return 1.0f/(1.0f+__expf(-v)); }
__device__ __forceinline__ float tanhx(float v){
  float e=__expf(-2.0f*fabsf(v)); float t=(1.0f-e)/(1.0f+e); return v<0.0f?-t:t;
}

// coherent (L1/L2-bypassing, L3-committed) store
__device__ __forceinline__ void st_coh(float* p, float v){
  asm volatile("global_store_dword %0, %1, off sc0 sc1" :: "v"(p), "v"(v) : "memory");
}
__device__ __forceinline__ void wait_vm0(){ asm volatile("s_waitcnt vmcnt(0)" ::: "memory"); }

// stage+transpose chunk ch of x[b][t][.] into sbuf[k_local][b], pitch LP
__device__ __forceinline__ void stageA(float* sbuf, const float* __restrict__ x,
                                       int t, int ch, int tid){
  #pragma unroll
  for(int it=0; it<2; ++it){
    int q  = it*NTHR + tid;          // 0..1023
    int b  = q >> 4;
    int k4 = (q & 15) << 2;
    const float4 v = *(const float4*)(x + ((size_t)b*Tlen + t)*Kd + ch*KC + k4);
    sbuf[(k4+0)*LP + b] = v.x;
    sbuf[(k4+1)*LP + b] = v.y;
    sbuf[(k4+2)*LP + b] = v.z;
    sbuf[(k4+3)*LP + b] = v.w;
  }
}

// Grid barrier, low-traffic edition.
// release: (sc0sc1 data stores) + vmcnt(0) + atomicAdd into counter[blockIdx&7]
//          (counters 64B apart; device-scope atomic commits at L3 after the drain).
// detect:  lane0 polls the 8 counters with ONE fused asm block (8 sectors = 512B),
//          sum >= 256*target. Other lanes/waves wait at reconvergence/syncthreads.
// acquire: all-wave agent fence (R1-identical semantics, known-correct).
// overlap: cell A pre-stages next tick's x chunk0 (read-only data, fence-safe).
__device__ __forceinline__ void grid_barrier(unsigned* cnt8, unsigned target, int tid,
                                             bool ps, float* sbuf,
                                             const float* __restrict__ x, int tn){
  wait_vm0();                 // my coherent stores are committed at L3
  __syncthreads();            // whole block done storing (and done reading smem)
  if(tid == 0) atomicAdd(cnt8 + ((blockIdx.x & 7) << 4), 1u);
  if(ps) stageA(sbuf, x, tn, 0, tid);          // overlap: stage next x chunk0
  if(tid == 0){
    const unsigned tgt = target << 8;          // 256 blocks total
    for(;;){
      unsigned c0,c1,c2,c3,c4,c5,c6,c7;
      asm volatile(
        "global_load_dword %0, %8, off sc0 sc1\n\t"
        "global_load_dword %1, %8, off offset:64 sc0 sc1\n\t"
        "global_load_dword %2, %8, off offset:128 sc0 sc1\n\t"
        "global_load_dword %3, %8, off offset:192 sc0 sc1\n\t"
        "global_load_dword %4, %8, off offset:256 sc0 sc1\n\t"
        "global_load_dword %5, %8, off offset:320 sc0 sc1\n\t"
        "global_load_dword %6, %8, off offset:384 sc0 sc1\n\t"
        "global_load_dword %7, %8, off offset:448 sc0 sc1\n\t"
        "s_waitcnt vmcnt(0)"
        : "=&v"(c0),"=&v"(c1),"=&v"(c2),"=&v"(c3),
          "=&v"(c4),"=&v"(c5),"=&v"(c6),"=&v"(c7)
        : "v"(cnt8) : "memory");
      if(((c0+c1)+(c2+c3))+((c4+c5)+(c6+c7)) >= tgt) break;
      __builtin_amdgcn_s_sleep(1);
    }
  }
  __syncthreads();
  __builtin_amdgcn_fence(__ATOMIC_ACQUIRE, "agent");  // inv vL1+L2 -> fresh normal loads
}

// 4-k-step of all 24 weight streams from LDS (broadcast b128 reads), FMA order
// bit-identical to the original per-k sequence.
__device__ __forceinline__ void gru_fma(const float* __restrict__ wlds, int kg,
                                        const float* xv, const float* hv,
                                        float* pr, float* pz, float* pni, float* pnh)
{
  float4 w[24];
  #pragma unroll
  for(int s = 0; s < 24; ++s)
    w[s] = *(const float4*)(wlds + s*Kd + kg);
  #pragma unroll
  for(int u = 0; u < 4; ++u){
    #pragma unroll
    for(int c = 0; c < 4; ++c){
      pr[c]  = fmaf(xv[u], (&w[     c].x)[u], pr[c]);
      pz[c]  = fmaf(xv[u], (&w[ 4 + c].x)[u], pz[c]);
      pni[c] = fmaf(xv[u], (&w[ 8 + c].x)[u], pni[c]);
      pr[c]  = fmaf(hv[u], (&w[12 + c].x)[u], pr[c]);
      pz[c]  = fmaf(hv[u], (&w[16 + c].x)[u], pz[c]);
      pnh[c] = fmaf(hv[u], (&w[20 + c].x)[u], pnh[c]);
    }
  }
}

extern "C" __global__ void __launch_bounds__(NTHR, 2)
gru_persist(const float* __restrict__ x,     // [B,T,IN]
            const float* __restrict__ eh,    // [L,B,H]
            const float* __restrict__ Wih,   // [L,3H,IN]
            const float* __restrict__ Whh,   // [L,3H,H]
            const float* __restrict__ bih,   // [L,3H]
            const float* __restrict__ bhh,   // [L,3H]
            float* __restrict__ out,         // [B,T,H] ++ [L,B,H]
            float* __restrict__ ws)
{
  __shared__ float smem[2*KC*LP];   // A: x staging dbuf; reused as reduction buffer
  __shared__ float wlds[24*Kd];     // 48KB: this block's weights, stream s = mat*12+g*4+c

  unsigned* cnt8 = (unsigned*)ws;             // 8 counters, 64B apart (first 512B)
  float* h0T = ws + 256;                      // 2 bufs x [512][64]
  float* h1T = h0T + 2*Kd*Bsz;
  float* htail = out + (size_t)Bsz*Tlen*Hd;

  const int tid  = threadIdx.x;
  const int lane = tid & 63;                                   // batch
  const int wv   = __builtin_amdgcn_readfirstlane(tid >> 6);   // wave id 0..7
  const int cell = blockIdx.x >> 7;                            // 0=layer0, 1=layer1
  const int cb   = blockIdx.x & 127;
  const int col0 = cb * 4;                                     // block's 4 cols
  unsigned bar = 1;

  // ---- one-time: stage this block's 24 weight rows into LDS ----
  {
    const float* WiC = Wih + (size_t)cell*3*Hd*Kd;
    const float* WhC = Whh + (size_t)cell*3*Hd*Kd;
    #pragma unroll 1
    for(int i = tid; i < 24*(Kd/4); i += NTHR){  // 3072 float4s, 6 iters/thread
      const int s   = i >> 7;                    // stream 0..23
      const int k4  = (i & 127) << 2;
      const int mat = (s >= 12);
      const int r   = s - 12*mat;
      const int g   = r >> 2, c = r & 3;
      const float* src = (mat ? WhC : WiC) + ((size_t)(g*Hd + col0 + c))*Kd + k4;
      *(float4*)(wlds + (size_t)s*Kd + k4) = *(const float4*)src;
    }
  }

  // ---- init: encoder_h -> parity-1 state bufs, transposed [k][b], coherent ----
  {
    int i = blockIdx.x*NTHR + tid;            // 131072 threads, 65536 items
    if(i < 2*Kd*Bsz){
      int l = i >> 15, k = (i >> 6) & 511, b = i & 63;
      float v = eh[(size_t)(l*Bsz + b)*Hd + k];
      st_coh((l ? h1T : h0T) + Kd*Bsz + k*Bsz + b, v);
    }
  }
  grid_barrier(cnt8, bar, tid, cell==0, smem, x, 0); bar++;   // pre-stages x(t=0) ch0

  // epilogue biases for this wave's col (clamped for waves 4..7; unused there)
  const int ec = wv & 3;
  const int ecol = col0 + ec;
  const float bi0 = bih[cell*1536 + 0*Hd + ecol] + bhh[cell*1536 + 0*Hd + ecol];
  const float bi1 = bih[cell*1536 + 1*Hd + ecol] + bhh[cell*1536 + 1*Hd + ecol];
  const float bi2 = bih[cell*1536 + 2*Hd + ecol];
  const float bh2 = bhh[cell*1536 + 2*Hd + ecol];

  for(int t = 0; t <= Tlen; ++t){
    const bool active = (cell == 0) ? (t < Tlen) : (t >= 1);
    if(active){
      const int s = (cell == 0) ? t : (t - 1);
      float* hbase = (cell == 0) ? h0T : h1T;
      const float* hprev = hbase + ((s+1)&1)*Kd*Bsz;
      float*       hout  = hbase + (s&1)*Kd*Bsz;
      const float* inT   = h0T + (s&1)*Kd*Bsz;      // cell B input (written by A last tick)

      float pr[4]={0,0,0,0}, pz[4]={0,0,0,0}, pni[4]={0,0,0,0}, pnh[4]={0,0,0,0};

      if(cell == 0){
        // x chunk0 pre-staged in the barrier; h direct global (cached, post-fence);
        // weights broadcast from LDS.
        #pragma unroll
        for(int ch = 0; ch < 8; ++ch){
          const float* cur = smem + (ch&1)*(KC*LP);
          if(ch < 7) stageA(smem + ((ch+1)&1)*(KC*LP), x, t, ch+1, tid);
          #pragma unroll
          for(int jj = 0; jj < 8; jj += 4){
            const int kl = (wv<<3) + jj;         // wave's interleaved sub-slice
            const int kg = (ch<<6) + kl;
            float xv[4], hv[4];
            #pragma unroll
            for(int u = 0; u < 4; ++u){
              xv[u] = cur[(kl+u)*LP + lane];
              hv[u] = hprev[(kg+u)*Bsz + lane];
            }
            gru_fma(wlds, kg, xv, hv, pr, pz, pni, pnh);
          }
          __syncthreads();
        }
      } else {
        // both act streams direct from [k][b] global (coalesced, cached post-fence);
        // weights broadcast from LDS.
        const int kg0 = (wv<<6);                 // contiguous K-octant
        #pragma unroll 1
        for(int j4 = 0; j4 < 64; j4 += 4){
          const int kg = kg0 + j4;
          float xv[4], hv[4];
          #pragma unroll
          for(int u = 0; u < 4; ++u){
            xv[u] = inT[(kg+u)*Bsz + lane];
            hv[u] = hprev[(kg+u)*Bsz + lane];
          }
          gru_fma(wlds, kg, xv, hv, pr, pz, pni, pnh);
        }
        __syncthreads();   // match A's pre-reduction state (smem free)
      }

      // ---- ksplit-8 reduction via LDS (aliases smem; guarded by syncs) ----
      float* red = smem;   // [(c*4+p)*8 + w][64]
      #pragma unroll
      for(int c = 0; c < 4; ++c){
        red[(((c<<2)+0)*8 + wv)*64 + lane] = pr[c];
        red[(((c<<2)+1)*8 + wv)*64 + lane] = pz[c];
        red[(((c<<2)+2)*8 + wv)*64 + lane] = pni[c];
        red[(((c<<2)+3)*8 + wv)*64 + lane] = pnh[c];
      }
      __syncthreads();
      if(wv < 4){
        const int c = wv;
        float spr=0.f, spz=0.f, spni=0.f, spnh=0.f;
        #pragma unroll
        for(int w = 0; w < 8; ++w){
          spr  += red[(((c<<2)+0)*8 + w)*64 + lane];
          spz  += red[(((c<<2)+1)*8 + w)*64 + lane];
          spni += red[(((c<<2)+2)*8 + w)*64 + lane];
          spnh += red[(((c<<2)+3)*8 + w)*64 + lane];
        }
        const int col = col0 + c;
        const float hkeep = hprev[col*Bsz + lane];
        const float r = sigf(spr + bi0);
        const float z = sigf(spz + bi1);
        const float n = tanhx(spni + bi2 + r*(spnh + bh2));
        const float hnew = (1.0f - z)*n + z*hkeep;
        st_coh(hout + col*Bsz + lane, hnew);                       // coherent, 256B/wave
        if(cell == 1)
          out[((size_t)lane*Tlen + s)*Hd + col] = hnew;            // normal store
      }
    }
    grid_barrier(cnt8, bar, tid, cell==0 && (t+1) < Tlen, smem, x, t+1); bar++;
  }

  // ---- tail: htail[l][b][c] from parity-1 bufs (post-fence normal loads) ----
  {
    int i = blockIdx.x*NTHR + tid;
    if(i < 2*Kd*Bsz){
      int l = i >> 15, b = (i >> 9) & 63, c = i & 511;
      const float* src = (l ? h1T : h0T) + Kd*Bsz;
      htail[i] = src[c*Bsz + b];
    }
  }
}

extern "C" void kernel_launch(void* const* d_in, const int* in_sizes, int n_in,
                              void* d_out, int out_size, void* d_ws, size_t ws_size,
                              hipStream_t stream) {
  (void)in_sizes; (void)n_in; (void)out_size; (void)ws_size;
  const float* x   = (const float*)d_in[0];
  const float* eh  = (const float*)d_in[1];
  const float* Wih = (const float*)d_in[2];
  const float* Whh = (const float*)d_in[3];
  const float* bih = (const float*)d_in[4];
  const float* bhh = (const float*)d_in[5];
  float* out = (float*)d_out;
  float* ws  = (float*)d_ws;

  hipMemsetAsync(d_ws, 0, 1024, stream);   // zero barrier counters

  void* args[] = {(void*)&x, (void*)&eh, (void*)&Wih, (void*)&Whh,
                  (void*)&bih, (void*)&bhh, (void*)&out, (void*)&ws};
  hipLaunchCooperativeKernel((const void*)gru_persist, dim3(NBLK), dim3(NTHR),
                             args, 0, stream);
}

// Round 9
// 35601.926 us; speedup vs baseline: 5.3740x; 1.1727x over previous
//
#include <hip/hip_runtime.h>

// GRU decoder B=64,T=512,IN=H=512,L=2. Persistent pipelined grid:
//   blocks [0,128)  = cell A (layer0 @ t),  blocks [128,256) = cell B (layer1 @ t-1)
// 256 blocks x 512 threads (1 block/CU, 8 waves). Block = 4 cols; wave = K-octant.
// Weights in LDS (48KB). h-state in d_ws [k][b], written sc0sc1 (write-through to
// L3 = coherence point), read with NORMAL cached loads after per-tick acquire fence.
//
// R9: FENCE COUNT 2048 -> 256. R8 falsified the poll-storm theory (R1's slot poll
// is L3-served; making it atomic/HBM-resident was 2.1x WORSE). The one component
// never varied across R0/R1/R8 is the per-wave agent acquire fence (buffer_inv from
// all 8 waves of all 256 blocks per tick). buffer_inv invalidates the PHYSICAL
// CU-L1/XCD-L2, so one inv per CU suffices: wave0 executes it after poll detect,
// the closing __syncthreads orders it before other waves' loads.
// Also: cell A's next-tick x chunk0 is staged inside the barrier (waves 1-7 stage
// while wave0 polls) -> serial stage off the tick's critical path. Rest = R1 verbatim.

#define NBLK 256
#define NTHR 512
#define Bsz  64
#define Tlen 512
#define Kd   512
#define Hd   512
#define KC   64
#define LP   67   // LDS pitch: scalar transpose writes land 2-way max (free)

__device__ __forceinline__ float sigf(float v){ return 1.0f/(1.0f+__expf(-v)); }
__device__ __forceinline__ float tanhx(float v){
  float e=__expf(-2.0f*fabsf(v)); float t=(1.0f-e)/(1.0f+e); return v<0.0f?-t:t;
}
__device__ __forceinline__ unsigned umin2(unsigned a, unsigned b){ return a<b?a:b; }

// coherent (L1/L2-bypassing, L3-committed) store
__device__ __forceinline__ void st_coh(float* p, float v){
  asm volatile("global_store_dword %0, %1, off sc0 sc1" :: "v"(p), "v"(v) : "memory");
}
__device__ __forceinline__ void st_coh_u(unsigned* p, unsigned v){
  asm volatile("global_store_dword %0, %1, off sc0 sc1" :: "v"(p), "v"(v) : "memory");
}
__device__ __forceinline__ void wait_vm0(){ asm volatile("s_waitcnt vmcnt(0)" ::: "memory"); }

// stage+transpose chunk ch of x[b][t][.] into sbuf[k_local][b], pitch LP
__device__ __forceinline__ void stageA(float* sbuf, const float* __restrict__ x,
                                       int t, int ch, int tid){
  #pragma unroll
  for(int it=0; it<2; ++it){
    int q  = it*NTHR + tid;          // 0..1023
    int b  = q >> 4;
    int k4 = (q & 15) << 2;
    const float4 v = *(const float4*)(x + ((size_t)b*Tlen + t)*Kd + ch*KC + k4);
    sbuf[(k4+0)*LP + b] = v.x;
    sbuf[(k4+1)*LP + b] = v.y;
    sbuf[(k4+2)*LP + b] = v.z;
    sbuf[(k4+3)*LP + b] = v.w;
  }
}

// Grid barrier (R1 structure): release = sc0sc1 data stores + vmcnt(0) + slot store.
// detect = wave0 polls all 256 slots (sc0sc1 loads, L3-served) + min-reduce.
// acquire = buffer_inv by WAVE0 ONLY (one per CU; invalidates physical L1/L2),
//           ordered before other waves' loads by the closing __syncthreads.
// overlap = waves 1-7 of cell-A blocks stage next tick's x chunk0 while wave0 polls.
__device__ __forceinline__ void grid_barrier(unsigned* slots, unsigned target, int tid,
                                             bool ps, float* sbuf,
                                             const float* __restrict__ x, int tn){
  wait_vm0();                 // every wave: my coherent stores are committed at L3
  __syncthreads();            // whole block done storing (and done reading smem)
  if(tid == 0) st_coh_u(slots + blockIdx.x, target);
  if(ps) stageA(sbuf, x, tn, 0, tid);          // overlap: stage next x chunk0
  if(tid < 64){
    const unsigned* p0 = slots + tid;
    for(;;){
      unsigned a,b,c,d;
      asm volatile(
        "global_load_dword %0, %4, off sc0 sc1\n\t"
        "global_load_dword %1, %5, off sc0 sc1\n\t"
        "global_load_dword %2, %6, off sc0 sc1\n\t"
        "global_load_dword %3, %7, off sc0 sc1\n\t"
        "s_waitcnt vmcnt(0)"
        : "=&v"(a),"=&v"(b),"=&v"(c),"=&v"(d)
        : "v"(p0), "v"(p0+64), "v"(p0+128), "v"(p0+192)
        : "memory");
      unsigned m = umin2(umin2(a,b), umin2(c,d));
      #pragma unroll
      for(int off=32; off; off>>=1)
        m = umin2(m, (unsigned)__shfl_xor((int)m, off, 64));
      if(m >= target) break;
      __builtin_amdgcn_s_sleep(1);
    }
    __builtin_amdgcn_fence(__ATOMIC_ACQUIRE, "agent");  // ONE inv per CU (wave0)
  }
  __syncthreads();            // orders the inv before all other waves' loads
}

// 4-k-step of all 24 weight streams from LDS (broadcast b128 reads), FMA order
// bit-identical to the original per-k sequence.
__device__ __forceinline__ void gru_fma(const float* __restrict__ wlds, int kg,
                                        const float* xv, const float* hv,
                                        float* pr, float* pz, float* pni, float* pnh)
{
  float4 w[24];
  #pragma unroll
  for(int s = 0; s < 24; ++s)
    w[s] = *(const float4*)(wlds + s*Kd + kg);
  #pragma unroll
  for(int u = 0; u < 4; ++u){
    #pragma unroll
    for(int c = 0; c < 4; ++c){
      pr[c]  = fmaf(xv[u], (&w[     c].x)[u], pr[c]);
      pz[c]  = fmaf(xv[u], (&w[ 4 + c].x)[u], pz[c]);
      pni[c] = fmaf(xv[u], (&w[ 8 + c].x)[u], pni[c]);
      pr[c]  = fmaf(hv[u], (&w[12 + c].x)[u], pr[c]);
      pz[c]  = fmaf(hv[u], (&w[16 + c].x)[u], pz[c]);
      pnh[c] = fmaf(hv[u], (&w[20 + c].x)[u], pnh[c]);
    }
  }
}

extern "C" __global__ void __launch_bounds__(NTHR, 2)
gru_persist(const float* __restrict__ x,     // [B,T,IN]
            const float* __restrict__ eh,    // [L,B,H]
            const float* __restrict__ Wih,   // [L,3H,IN]
            const float* __restrict__ Whh,   // [L,3H,H]
            const float* __restrict__ bih,   // [L,3H]
            const float* __restrict__ bhh,   // [L,3H]
            float* __restrict__ out,         // [B,T,H] ++ [L,B,H]
            float* __restrict__ ws)
{
  __shared__ float smem[2*KC*LP];   // A: x staging dbuf; reused as reduction buffer
  __shared__ float wlds[24*Kd];     // 48KB: this block's weights, stream s = mat*12+g*4+c

  unsigned* slots = (unsigned*)ws;            // 256 monotonic tick slots
  float* h0T = ws + 256;                      // 2 bufs x [512][64]
  float* h1T = h0T + 2*Kd*Bsz;
  float* htail = out + (size_t)Bsz*Tlen*Hd;

  const int tid  = threadIdx.x;
  const int lane = tid & 63;                                   // batch
  const int wv   = __builtin_amdgcn_readfirstlane(tid >> 6);   // wave id 0..7
  const int cell = blockIdx.x >> 7;                            // 0=layer0, 1=layer1
  const int cb   = blockIdx.x & 127;
  const int col0 = cb * 4;                                     // block's 4 cols
  unsigned bar = 1;

  // ---- one-time: stage this block's 24 weight rows into LDS ----
  {
    const float* WiC = Wih + (size_t)cell*3*Hd*Kd;
    const float* WhC = Whh + (size_t)cell*3*Hd*Kd;
    #pragma unroll 1
    for(int i = tid; i < 24*(Kd/4); i += NTHR){  // 3072 float4s, 6 iters/thread
      const int s   = i >> 7;                    // stream 0..23
      const int k4  = (i & 127) << 2;
      const int mat = (s >= 12);
      const int r   = s - 12*mat;
      const int g   = r >> 2, c = r & 3;
      const float* src = (mat ? WhC : WiC) + ((size_t)(g*Hd + col0 + c))*Kd + k4;
      *(float4*)(wlds + (size_t)s*Kd + k4) = *(const float4*)src;
    }
  }

  // ---- init: encoder_h -> parity-1 state bufs, transposed [k][b], coherent ----
  {
    int i = blockIdx.x*NTHR + tid;            // 131072 threads, 65536 items
    if(i < 2*Kd*Bsz){
      int l = i >> 15, k = (i >> 6) & 511, b = i & 63;
      float v = eh[(size_t)(l*Bsz + b)*Hd + k];
      st_coh((l ? h1T : h0T) + Kd*Bsz + k*Bsz + b, v);
    }
  }
  grid_barrier(slots, bar, tid, cell==0, smem, x, 0); bar++;   // prestages x(t=0) ch0

  // epilogue biases for this wave's col (clamped for waves 4..7; unused there)
  const int ec = wv & 3;
  const int ecol = col0 + ec;
  const float bi0 = bih[cell*1536 + 0*Hd + ecol] + bhh[cell*1536 + 0*Hd + ecol];
  const float bi1 = bih[cell*1536 + 1*Hd + ecol] + bhh[cell*1536 + 1*Hd + ecol];
  const float bi2 = bih[cell*1536 + 2*Hd + ecol];
  const float bh2 = bhh[cell*1536 + 2*Hd + ecol];

  for(int t = 0; t <= Tlen; ++t){
    const bool active = (cell == 0) ? (t < Tlen) : (t >= 1);
    if(active){
      const int s = (cell == 0) ? t : (t - 1);
      float* hbase = (cell == 0) ? h0T : h1T;
      const float* hprev = hbase + ((s+1)&1)*Kd*Bsz;
      float*       hout  = hbase + (s&1)*Kd*Bsz;
      const float* inT   = h0T + (s&1)*Kd*Bsz;      // cell B input (written by A last tick)

      float pr[4]={0,0,0,0}, pz[4]={0,0,0,0}, pni[4]={0,0,0,0}, pnh[4]={0,0,0,0};

      if(cell == 0){
        // x chunk0 pre-staged in the barrier; h direct global (cached, post-fence);
        // weights broadcast from LDS.
        #pragma unroll
        for(int ch = 0; ch < 8; ++ch){
          const float* cur = smem + (ch&1)*(KC*LP);
          if(ch < 7) stageA(smem + ((ch+1)&1)*(KC*LP), x, t, ch+1, tid);
          #pragma unroll
          for(int jj = 0; jj < 8; jj += 4){
            const int kl = (wv<<3) + jj;         // wave's interleaved sub-slice
            const int kg = (ch<<6) + kl;
            float xv[4], hv[4];
            #pragma unroll
            for(int u = 0; u < 4; ++u){
              xv[u] = cur[(kl+u)*LP + lane];
              hv[u] = hprev[(kg+u)*Bsz + lane];
            }
            gru_fma(wlds, kg, xv, hv, pr, pz, pni, pnh);
          }
          __syncthreads();
        }
      } else {
        // both act streams direct from [k][b] global (coalesced, cached post-fence);
        // weights broadcast from LDS.
        const int kg0 = (wv<<6);                 // contiguous K-octant
        #pragma unroll 1
        for(int j4 = 0; j4 < 64; j4 += 4){
          const int kg = kg0 + j4;
          float xv[4], hv[4];
          #pragma unroll
          for(int u = 0; u < 4; ++u){
            xv[u] = inT[(kg+u)*Bsz + lane];
            hv[u] = hprev[(kg+u)*Bsz + lane];
          }
          gru_fma(wlds, kg, xv, hv, pr, pz, pni, pnh);
        }
        __syncthreads();   // match A's pre-reduction state (smem free)
      }

      // ---- ksplit-8 reduction via LDS (aliases smem; guarded by syncs) ----
      float* red = smem;   // [(c*4+p)*8 + w][64]
      #pragma unroll
      for(int c = 0; c < 4; ++c){
        red[(((c<<2)+0)*8 + wv)*64 + lane] = pr[c];
        red[(((c<<2)+1)*8 + wv)*64 + lane] = pz[c];
        red[(((c<<2)+2)*8 + wv)*64 + lane] = pni[c];
        red[(((c<<2)+3)*8 + wv)*64 + lane] = pnh[c];
      }
      __syncthreads();
      if(wv < 4){
        const int c = wv;
        float spr=0.f, spz=0.f, spni=0.f, spnh=0.f;
        #pragma unroll
        for(int w = 0; w < 8; ++w){
          spr  += red[(((c<<2)+0)*8 + w)*64 + lane];
          spz  += red[(((c<<2)+1)*8 + w)*64 + lane];
          spni += red[(((c<<2)+2)*8 + w)*64 + lane];
          spnh += red[(((c<<2)+3)*8 + w)*64 + lane];
        }
        const int col = col0 + c;
        const float hkeep = hprev[col*Bsz + lane];
        const float r = sigf(spr + bi0);
        const float z = sigf(spz + bi1);
        const float n = tanhx(spni + bi2 + r*(spnh + bh2));
        const float hnew = (1.0f - z)*n + z*hkeep;
        st_coh(hout + col*Bsz + lane, hnew);                       // coherent, 256B/wave
        if(cell == 1)
          out[((size_t)lane*Tlen + s)*Hd + col] = hnew;            // normal store
      }
    }
    grid_barrier(slots, bar, tid, cell==0 && (t+1) < Tlen, smem, x, t+1); bar++;
  }

  // ---- tail: htail[l][b][c] from parity-1 bufs (post-fence normal loads) ----
  {
    int i = blockIdx.x*NTHR + tid;
    if(i < 2*Kd*Bsz){
      int l = i >> 15, b = (i >> 9) & 63, c = i & 511;
      const float* src = (l ? h1T : h0T) + Kd*Bsz;
      htail[i] = src[c*Bsz + b];
    }
  }
}

extern "C" void kernel_launch(void* const* d_in, const int* in_sizes, int n_in,
                              void* d_out, int out_size, void* d_ws, size_t ws_size,
                              hipStream_t stream) {
  (void)in_sizes; (void)n_in; (void)out_size; (void)ws_size;
  const float* x   = (const float*)d_in[0];
  const float* eh  = (const float*)d_in[1];
  const float* Wih = (const float*)d_in[2];
  const float* Whh = (const float*)d_in[3];
  const float* bih = (const float*)d_in[4];
  const float* bhh = (const float*)d_in[5];
  float* out = (float*)d_out;
  float* ws  = (float*)d_ws;

  hipMemsetAsync(d_ws, 0, 1024, stream);   // zero barrier slots

  void* args[] = {(void*)&x, (void*)&eh, (void*)&Wih, (void*)&Whh,
                  (void*)&bih, (void*)&bhh, (void*)&out, (void*)&ws};
  hipLaunchCooperativeKernel((const void*)gru_persist, dim3(NBLK), dim3(NTHR),
                             args, 0, stream);
}